// Round 2
// baseline (484.217 us; speedup 1.0000x reference)
//
#include <hip/hip_runtime.h>

namespace {
constexpr int Sdim = 128;
constexpr int Tdim = 64;
constexpr int U2c  = 16;
constexpr int PT   = 16;                 // pixel locations per block
constexpr int NTHREADS = 256;
constexpr int PP = Sdim * Sdim;          // 16384 pixels
constexpr int THALF = 32;                // t-steps staged per phase (LDS = 32 KiB)
}

__global__ __launch_bounds__(NTHREADS, 4)
void upscale_fused(const float* __restrict__ yt,
                   const float* __restrict__ wgt,
                   const float* __restrict__ bias,
                   float* __restrict__ out)
{
    // [t_local][u][p_local], p fastest. 32 KiB -> 4 blocks/CU (vs 64 KiB -> 2).
    __shared__ float wlds[THALF * U2c * PT];

    const int tid   = threadIdx.x;
    const int p_blk = blockIdx.x * PT;

    // ---- staging helper: half h covers t in [h*32, h*32+32) --------------------
    auto stage = [&](int h) {
        const int sp = tid & (PT - 1);      // p_local 0..15
        const int sj = tid >> 4;            // 0..15
        const float* src = wgt + (size_t)(p_blk + sp) * (Tdim * U2c)
                               + h * (THALF * U2c) + sj * 32;
        #pragma unroll
        for (int k = 0; k < 8; ++k) {
            const float4 v = *reinterpret_cast<const float4*>(src + k * 4);
            const int off = sj * 32 + k * 4;          // = t_local*16 + u0
            wlds[(off + 0) * PT + sp] = v.x;
            wlds[(off + 1) * PT + sp] = v.y;
            wlds[(off + 2) * PT + sp] = v.z;
            wlds[(off + 3) * PT + sp] = v.w;
        }
    };

    // ---- thread mapping: 4p x 2b x 8u per thread --------------------------------
    const int pg = tid & 3;            // p0 = p_blk + pg*4 .. +3
    const int b2 = (tid >> 2) & 31;    // b in {b2, b2+32}
    const int ug = tid >> 7;           // u = ug*8 + v, v in [0,8)
    const int p0 = p_blk + pg * 4;

    stage(0);

    // ---- init acc with bias (same bias for both b) ------------------------------
    float acc[2][4][8];
    #pragma unroll
    for (int j = 0; j < 4; ++j) {
        const float* bp = bias + (size_t)(p0 + j) * U2c + ug * 8;
        const float4 v0 = *reinterpret_cast<const float4*>(bp);
        const float4 v1 = *reinterpret_cast<const float4*>(bp + 4);
        const float bb[8] = {v0.x, v0.y, v0.z, v0.w, v1.x, v1.y, v1.z, v1.w};
        #pragma unroll
        for (int v = 0; v < 8; ++v) { acc[0][j][v] = bb[v]; acc[1][j][v] = bb[v]; }
    }

    // ---- depth-4 yt prefetch ring (static-indexed) ------------------------------
    const float* y0base = yt + (size_t)b2 * (Tdim * PP) + p0;
    const float* y1base = y0base + (size_t)32 * (Tdim * PP);

    float4 yq0[4], yq1[4];
    #pragma unroll
    for (int k = 0; k < 4; ++k) {
        yq0[k] = *reinterpret_cast<const float4*>(y0base + (size_t)k * PP);
        yq1[k] = *reinterpret_cast<const float4*>(y1base + (size_t)k * PP);
    }

    __syncthreads();   // stage(0) visible

    auto compute_half = [&](int h) {
        for (int tb = 0; tb < THALF; tb += 4) {
            #pragma unroll
            for (int k = 0; k < 4; ++k) {
                const int tl = tb + k;
                const int tg = h * THALF + tl;
                const int tf = (tg + 4 < Tdim) ? (tg + 4) : (Tdim - 1);
                const float4 f0 = *reinterpret_cast<const float4*>(y0base + (size_t)tf * PP);
                const float4 f1 = *reinterpret_cast<const float4*>(y1base + (size_t)tf * PP);

                const float ya[4] = {yq0[k].x, yq0[k].y, yq0[k].z, yq0[k].w};
                const float yb[4] = {yq1[k].x, yq1[k].y, yq1[k].z, yq1[k].w};

                const float* wrow = &wlds[(size_t)(tl * U2c + ug * 8) * PT + pg * 4];
                #pragma unroll
                for (int v = 0; v < 8; ++v) {
                    const float4 wv = *reinterpret_cast<const float4*>(wrow + v * PT);
                    acc[0][0][v] = fmaf(ya[0], wv.x, acc[0][0][v]);
                    acc[0][1][v] = fmaf(ya[1], wv.y, acc[0][1][v]);
                    acc[0][2][v] = fmaf(ya[2], wv.z, acc[0][2][v]);
                    acc[0][3][v] = fmaf(ya[3], wv.w, acc[0][3][v]);
                    acc[1][0][v] = fmaf(yb[0], wv.x, acc[1][0][v]);
                    acc[1][1][v] = fmaf(yb[1], wv.y, acc[1][1][v]);
                    acc[1][2][v] = fmaf(yb[2], wv.z, acc[1][2][v]);
                    acc[1][3][v] = fmaf(yb[3], wv.w, acc[1][3][v]);
                }
                yq0[k] = f0; yq1[k] = f1;
            }
        }
    };

    compute_half(0);
    __syncthreads();   // all waves done reading half 0
    stage(1);
    __syncthreads();   // stage(1) visible
    compute_half(1);

    // ---- epilogue: pixel-shuffle scatter, 64B contiguous per lane ---------------
    const int s1   = p_blk / Sdim;
    const int s2_0 = p_blk % Sdim;

    #pragma unroll
    for (int bi = 0; bi < 2; ++bi) {
        const int b = b2 + bi * 32;
        float* ob = out + (size_t)b * (512 * 512);
        #pragma unroll
        for (int u1l = 0; u1l < 2; ++u1l) {
            const int r = s1 * 4 + (ug * 2 + u1l);
            #pragma unroll
            for (int j = 0; j < 4; ++j) {
                const int c0 = (s2_0 + pg * 4 + j) * 4;
                float4 v;
                v.x = acc[bi][j][u1l * 4 + 0];
                v.y = acc[bi][j][u1l * 4 + 1];
                v.z = acc[bi][j][u1l * 4 + 2];
                v.w = acc[bi][j][u1l * 4 + 3];
                *reinterpret_cast<float4*>(ob + (size_t)r * 512 + c0) = v;
            }
        }
    }
}

extern "C" void kernel_launch(void* const* d_in, const int* in_sizes, int n_in,
                              void* d_out, int out_size, void* d_ws, size_t ws_size,
                              hipStream_t stream)
{
    const float* yt   = (const float*)d_in[0];
    const float* wgt  = (const float*)d_in[1];
    const float* bias = (const float*)d_in[2];
    float* outp       = (float*)d_out;

    dim3 grid(PP / PT);     // 1024 blocks
    dim3 block(NTHREADS);
    hipLaunchKernelGGL(upscale_fused, grid, block, 0, stream, yt, wgt, bias, outp);
}

// Round 3
// 162.674 us; speedup vs baseline: 2.9766x; 2.9766x over previous
//
#include <hip/hip_runtime.h>

namespace {
constexpr int Sdim = 128;
constexpr int Tdim = 64;
constexpr int U2c  = 16;
constexpr int PT   = 16;                 // pixel locations per block
constexpr int NTHREADS = 256;
constexpr int PP = Sdim * Sdim;          // 16384 pixels
constexpr int THALF = 32;                // t-steps staged per phase (LDS = 32 KiB)
}

// (256,2): VGPR cap 256 -> compiler uses ~88, NO spill (R2's (256,4) clamped to 64
// VGPR and spilled 1.2 GB of scratch traffic to HBM). 88 <= 128 still permits
// 4 waves/SIMD; occupancy = min(LDS 160/32=5, VGPR 4) = 4 blocks/CU.
__global__ __launch_bounds__(NTHREADS, 2)
void upscale_fused(const float* __restrict__ yt,
                   const float* __restrict__ wgt,
                   const float* __restrict__ bias,
                   float* __restrict__ out)
{
    // [t_local][u][p_local], p fastest: compute reads ds_read_b128 over 4
    // consecutive p -> 4 unique addrs/wave, 16-lane broadcast, conflict-free.
    __shared__ float wlds[THALF * U2c * PT];   // 32 KiB

    const int tid   = threadIdx.x;
    const int p_blk = blockIdx.x * PT;

    // ---- stage weights for t in [h*32, h*32+32) ---------------------------------
    auto stage = [&](int h) {
        const int sp = tid & (PT - 1);      // p_local 0..15
        const int sj = tid >> 4;            // 0..15
        const float* src = wgt + (size_t)(p_blk + sp) * (Tdim * U2c)
                               + h * (THALF * U2c) + sj * 32;
        #pragma unroll
        for (int k = 0; k < 8; ++k) {
            const float4 v = *reinterpret_cast<const float4*>(src + k * 4);
            const int off = sj * 32 + k * 4;          // = t_local*16 + u0
            wlds[(off + 0) * PT + sp] = v.x;
            wlds[(off + 1) * PT + sp] = v.y;
            wlds[(off + 2) * PT + sp] = v.z;
            wlds[(off + 3) * PT + sp] = v.w;
        }
    };

    // ---- thread mapping: 4p x 2b x 8u per thread --------------------------------
    const int pg = tid & 3;            // p0 = p_blk + pg*4 .. +3
    const int b2 = (tid >> 2) & 31;    // b in {b2, b2+32}
    const int ug = tid >> 7;           // u = ug*8 + v, v in [0,8)
    const int p0 = p_blk + pg * 4;

    stage(0);

    // ---- init acc with bias (same bias for both b) ------------------------------
    float acc[2][4][8];
    #pragma unroll
    for (int j = 0; j < 4; ++j) {
        const float* bp = bias + (size_t)(p0 + j) * U2c + ug * 8;
        const float4 v0 = *reinterpret_cast<const float4*>(bp);
        const float4 v1 = *reinterpret_cast<const float4*>(bp + 4);
        const float bb[8] = {v0.x, v0.y, v0.z, v0.w, v1.x, v1.y, v1.z, v1.w};
        #pragma unroll
        for (int v = 0; v < 8; ++v) { acc[0][j][v] = bb[v]; acc[1][j][v] = bb[v]; }
    }

    // ---- depth-2 yt prefetch ring (R1's proven 88-VGPR shape) -------------------
    const float* y0base = yt + (size_t)b2 * (Tdim * PP) + p0;
    const float* y1base = y0base + (size_t)32 * (Tdim * PP);

    float4 yc0 = *reinterpret_cast<const float4*>(y0base);
    float4 yc1 = *reinterpret_cast<const float4*>(y1base);
    float4 yn0 = *reinterpret_cast<const float4*>(y0base + PP);
    float4 yn1 = *reinterpret_cast<const float4*>(y1base + PP);

    __syncthreads();   // stage(0) visible

    #pragma unroll 1
    for (int h = 0; h < 2; ++h) {
        if (h == 1) {
            __syncthreads();   // all waves done reading half 0
            stage(1);
            __syncthreads();   // stage(1) visible
        }
        for (int tl = 0; tl < THALF; ++tl) {
            const int tg = h * THALF + tl;
            const int tf = (tg + 2 < Tdim) ? (tg + 2) : (Tdim - 1);
            const float4 yf0 = *reinterpret_cast<const float4*>(y0base + (size_t)tf * PP);
            const float4 yf1 = *reinterpret_cast<const float4*>(y1base + (size_t)tf * PP);

            const float ya[4] = {yc0.x, yc0.y, yc0.z, yc0.w};
            const float yb[4] = {yc1.x, yc1.y, yc1.z, yc1.w};

            const float* wrow = &wlds[(size_t)(tl * U2c + ug * 8) * PT + pg * 4];
            #pragma unroll
            for (int v = 0; v < 8; ++v) {
                const float4 wv = *reinterpret_cast<const float4*>(wrow + v * PT);
                acc[0][0][v] = fmaf(ya[0], wv.x, acc[0][0][v]);
                acc[0][1][v] = fmaf(ya[1], wv.y, acc[0][1][v]);
                acc[0][2][v] = fmaf(ya[2], wv.z, acc[0][2][v]);
                acc[0][3][v] = fmaf(ya[3], wv.w, acc[0][3][v]);
                acc[1][0][v] = fmaf(yb[0], wv.x, acc[1][0][v]);
                acc[1][1][v] = fmaf(yb[1], wv.y, acc[1][1][v]);
                acc[1][2][v] = fmaf(yb[2], wv.z, acc[1][2][v]);
                acc[1][3][v] = fmaf(yb[3], wv.w, acc[1][3][v]);
            }
            yc0 = yn0; yc1 = yn1; yn0 = yf0; yn1 = yf1;
        }
    }

    // ---- epilogue: pixel-shuffle scatter, 64B contiguous per lane ---------------
    const int s1   = p_blk / Sdim;
    const int s2_0 = p_blk % Sdim;

    #pragma unroll
    for (int bi = 0; bi < 2; ++bi) {
        const int b = b2 + bi * 32;
        float* ob = out + (size_t)b * (512 * 512);
        #pragma unroll
        for (int u1l = 0; u1l < 2; ++u1l) {
            const int r = s1 * 4 + (ug * 2 + u1l);
            #pragma unroll
            for (int j = 0; j < 4; ++j) {
                const int c0 = (s2_0 + pg * 4 + j) * 4;
                float4 v;
                v.x = acc[bi][j][u1l * 4 + 0];
                v.y = acc[bi][j][u1l * 4 + 1];
                v.z = acc[bi][j][u1l * 4 + 2];
                v.w = acc[bi][j][u1l * 4 + 3];
                *reinterpret_cast<float4*>(ob + (size_t)r * 512 + c0) = v;
            }
        }
    }
}

extern "C" void kernel_launch(void* const* d_in, const int* in_sizes, int n_in,
                              void* d_out, int out_size, void* d_ws, size_t ws_size,
                              hipStream_t stream)
{
    const float* yt   = (const float*)d_in[0];
    const float* wgt  = (const float*)d_in[1];
    const float* bias = (const float*)d_in[2];
    float* outp       = (float*)d_out;

    dim3 grid(PP / PT);     // 1024 blocks
    dim3 block(NTHREADS);
    hipLaunchKernelGGL(upscale_fused, grid, block, 0, stream, yt, wgt, bias, outp);
}

// Round 4
// 103.945 us; speedup vs baseline: 4.6584x; 1.5650x over previous
//
#include <hip/hip_runtime.h>

namespace {
constexpr int Sdim = 128;
constexpr int Tdim = 64;
constexpr int U2c  = 16;
constexpr int PT   = 32;                 // pixel locations per block (128B-contiguous yt rows)
constexpr int NTHREADS = 512;
constexpr int PP = Sdim * Sdim;          // 16384 pixels
constexpr int TQ = 16;                   // t-steps staged per phase (LDS = 32 KiB)
constexpr int NSTG = Tdim / TQ;          // 4 stages
}

// (512,2): VGPR cap 256 -> compiler free (~100 live), no spill (R2 lesson: never clamp).
__global__ __launch_bounds__(NTHREADS, 2)
void upscale_fused(const float* __restrict__ yt,
                   const float* __restrict__ wgt,
                   const float* __restrict__ bias,
                   float* __restrict__ out)
{
    // layout [t_local][u][p ^ (2*t_local)]: XOR swizzle keeps the f-linear coalesced
    // staging writes <=4-way and the compute float2 reads conflict-free (16 even cols
    // -> 32 banks, 4-lane broadcast). 32 KiB.
    __shared__ float wlds[TQ * U2c * PT];

    const int tid   = threadIdx.x;
    const int p_blk = blockIdx.x * PT;

    const int pg = tid & 15;            // 2 pixels: p0, p0+1
    const int b2 = (tid >> 4) & 31;     // b in {b2, b2+32}
    const int p0 = p_blk + pg * 2;

    // ---- stage weights for t in [stg*16, stg*16+16) -----------------------------
    // f-linear map: each wave instruction reads ONE contiguous 1024B run (8 full
    // 128B lines) -> max bytes per request slot.
    auto stage = [&](int stg) {
        const float4* wgt4 = reinterpret_cast<const float4*>(wgt);
        #pragma unroll
        for (int i = 0; i < 4; ++i) {
            const int f  = i * NTHREADS + tid;   // 0..2047 float4s of the 32KB tile
            const int r  = f >> 6;               // p row 0..31
            const int c  = f & 63;               // float4 within the 1KB p-row
            const int tw = c >> 2;               // t_local 0..15
            const int uq = c & 3;                // u quad
            const float4 v = wgt4[(size_t)(p_blk + r) * 256 + (size_t)stg * 64 + c];
            const int col = r ^ (2 * tw);
            float* dst = &wlds[(tw * U2c + uq * 4) * PT + col];
            dst[0 * PT] = v.x;  dst[1 * PT] = v.y;  dst[2 * PT] = v.z;  dst[3 * PT] = v.w;
        }
    };

    stage(0);

    // ---- init acc with bias (identical for both b) -------------------------------
    float acc[2][2][16];   // [b][jp][u]
    #pragma unroll
    for (int jp = 0; jp < 2; ++jp) {
        const float* bp = bias + (size_t)(p0 + jp) * U2c;
        const float4 q0 = *reinterpret_cast<const float4*>(bp + 0);
        const float4 q1 = *reinterpret_cast<const float4*>(bp + 4);
        const float4 q2 = *reinterpret_cast<const float4*>(bp + 8);
        const float4 q3 = *reinterpret_cast<const float4*>(bp + 12);
        const float bb[16] = {q0.x,q0.y,q0.z,q0.w, q1.x,q1.y,q1.z,q1.w,
                              q2.x,q2.y,q2.z,q2.w, q3.x,q3.y,q3.z,q3.w};
        #pragma unroll
        for (int u = 0; u < 16; ++u) { acc[0][jp][u] = bb[u]; acc[1][jp][u] = bb[u]; }
    }

    // ---- yt: float2 per (b,t), NO duplicate loads, wave = 4 x 128B segments ------
    const float* y0b = yt + (size_t)b2 * ((size_t)Tdim * PP) + p0;
    const float* y1b = y0b + (size_t)32 * Tdim * PP;
    auto ldy = [&](int t, float2& a, float2& b) {
        a = *reinterpret_cast<const float2*>(y0b + (size_t)t * PP);
        b = *reinterpret_cast<const float2*>(y1b + (size_t)t * PP);
    };

    auto step = [&](const float2& ya, const float2& yb, int tl) {
        const float* wrow = &wlds[tl * (U2c * PT) + ((pg * 2) ^ (2 * tl))];
        #pragma unroll
        for (int u = 0; u < 16; ++u) {
            const float2 wv = *reinterpret_cast<const float2*>(wrow + u * PT);
            acc[0][0][u] = fmaf(ya.x, wv.x, acc[0][0][u]);
            acc[0][1][u] = fmaf(ya.y, wv.y, acc[0][1][u]);
            acc[1][0][u] = fmaf(yb.x, wv.x, acc[1][0][u]);
            acc[1][1][u] = fmaf(yb.y, wv.y, acc[1][1][u]);
        }
    };

    // ---- depth-4 static ping-pong prefetch (no rotation moves) -------------------
    float2 A0, A1, B0, B1, C0, C1, D0, D1;
    ldy(0, A0, A1); ldy(1, B0, B1); ldy(2, C0, C1); ldy(3, D0, D1);

    __syncthreads();   // stage(0) visible

    #pragma unroll 1
    for (int stg = 0; stg < NSTG; ++stg) {
        if (stg) {
            __syncthreads();   // all waves done reading previous stage
            stage(stg);
            __syncthreads();   // new stage visible
        }
        #pragma unroll 1
        for (int tq = 0; tq < TQ; tq += 4) {
            const int tg = stg * TQ + tq;
            step(A0, A1, tq + 0); { const int tf = (tg + 4 < Tdim) ? tg + 4 : Tdim - 1; ldy(tf, A0, A1); }
            step(B0, B1, tq + 1); { const int tf = (tg + 5 < Tdim) ? tg + 5 : Tdim - 1; ldy(tf, B0, B1); }
            step(C0, C1, tq + 2); { const int tf = (tg + 6 < Tdim) ? tg + 6 : Tdim - 1; ldy(tf, C0, C1); }
            step(D0, D1, tq + 3); { const int tf = (tg + 7 < Tdim) ? tg + 7 : Tdim - 1; ldy(tf, D0, D1); }
        }
    }

    // ---- epilogue: pixel-shuffle scatter, 16B-contiguous per lane ----------------
    const int s1   = p_blk / Sdim;
    const int s2_0 = p_blk % Sdim;

    #pragma unroll
    for (int bi = 0; bi < 2; ++bi) {
        const int b = b2 + bi * 32;
        float* ob = out + (size_t)b * (512 * 512);
        #pragma unroll
        for (int jp = 0; jp < 2; ++jp) {
            const int c0 = (s2_0 + pg * 2 + jp) * 4;
            #pragma unroll
            for (int u1 = 0; u1 < 4; ++u1) {
                const int r = s1 * 4 + u1;
                float4 v;
                v.x = acc[bi][jp][u1 * 4 + 0];
                v.y = acc[bi][jp][u1 * 4 + 1];
                v.z = acc[bi][jp][u1 * 4 + 2];
                v.w = acc[bi][jp][u1 * 4 + 3];
                *reinterpret_cast<float4*>(ob + (size_t)r * 512 + c0) = v;
            }
        }
    }
}

extern "C" void kernel_launch(void* const* d_in, const int* in_sizes, int n_in,
                              void* d_out, int out_size, void* d_ws, size_t ws_size,
                              hipStream_t stream)
{
    const float* yt   = (const float*)d_in[0];
    const float* wgt  = (const float*)d_in[1];
    const float* bias = (const float*)d_in[2];
    float* outp       = (float*)d_out;

    dim3 grid(PP / PT);     // 512 blocks
    dim3 block(NTHREADS);
    hipLaunchKernelGGL(upscale_fused, grid, block, 0, stream, yt, wgt, bias, outp);
}